// Round 4
// baseline (73.020 us; speedup 1.0000x reference)
//
#include <hip/hip_runtime.h>
#include <hip/hip_cooperative_groups.h>

namespace cg = cooperative_groups;

#define N_NEUR 9216   // L*L
#define N_FEAT 1024
#define NBLK   1024   // 4 blocks/CU * 256 CU -> co-resident at <=128 VGPR
#define NTHR   256
#define ROWS   9      // 9216 / 1024, exact
#define LR 0.1f

// Fully fused SOM step. Block b owns rows [b*9, b*9+9). Phase 1 loads each W
// row into REGISTERS (float4/thread/row), computes dist^2, block-min packed
// key -> partials[b]. grid.sync. Phase 2: every block reduces the 1024
// partials (L2 broadcast) -> bmu. Phase 3: update from register-held W.
// W is read from HBM exactly once; single launch.
__global__ __launch_bounds__(NTHR, 4) void som_fused(
    const float* __restrict__ x, const float* __restrict__ W,
    const float* __restrict__ nhb, float* __restrict__ out,
    unsigned long long* __restrict__ partials)
{
    const int b  = blockIdx.x;
    const int t  = threadIdx.x;
    const int wv = t >> 6, ln = t & 63;

    __shared__ float red[4][ROWS];
    __shared__ unsigned long long wmin[4];

    const float4 xa = reinterpret_cast<const float4*>(x)[t];

    float4 wrow[ROWS];

    // ---- phase 1: dist^2 per owned row, W rows -> registers ----
    #pragma unroll
    for (int k = 0; k < ROWS; ++k) {
        const int row = b * ROWS + k;
        const float4 w = reinterpret_cast<const float4*>(W + (size_t)row * N_FEAT)[t];
        wrow[k] = w;
        const float dx = xa.x - w.x, dy = xa.y - w.y,
                    dz = xa.z - w.z, dw = xa.w - w.w;
        float s = dx * dx + dy * dy + dz * dz + dw * dw;
        #pragma unroll
        for (int o = 32; o > 0; o >>= 1) s += __shfl_down(s, o);
        if (ln == 0) red[wv][k] = s;
    }
    __syncthreads();

    if (t == 0) {
        unsigned long long lmin = ~0ull;
        #pragma unroll
        for (int k = 0; k < ROWS; ++k) {
            const float tot = red[0][k] + red[1][k] + red[2][k] + red[3][k];
            // dist2 >= 0: IEEE bits monotone as uint; ties -> smallest row
            const unsigned long long key =
                ((unsigned long long)__float_as_uint(tot) << 32)
                | (unsigned)(b * ROWS + k);
            lmin = key < lmin ? key : lmin;
        }
        partials[b] = lmin;
    }

    cg::this_grid().sync();

    // ---- phase 2: every block reduces 1024 partials -> bmu (broadcast) ----
    unsigned long long m = ~0ull;
    #pragma unroll
    for (int i = 0; i < NBLK / NTHR; ++i) {
        const unsigned long long k = partials[t + i * NTHR];
        m = k < m ? k : m;
    }
    #pragma unroll
    for (int o = 32; o > 0; o >>= 1) {
        const unsigned long long k = __shfl_down(m, o);
        m = k < m ? k : m;
    }
    if (ln == 0) wmin[wv] = m;
    __syncthreads();
    m = wmin[0];
    #pragma unroll
    for (int w2 = 1; w2 < 4; ++w2) m = wmin[w2] < m ? wmin[w2] : m;
    const unsigned bmu = (unsigned)(m & 0xFFFFFFFFu);

    // ---- phase 3: W_new = W + LR*h*(x-W) from register-held W ----
    #pragma unroll
    for (int k = 0; k < ROWS; ++k) {
        const int row = b * ROWS + k;
        const float lh = LR * expf(-0.5f * nhb[(size_t)bmu * N_NEUR + row]);
        const float4 w = wrow[k];
        float4 r;
        r.x = w.x + lh * (xa.x - w.x);
        r.y = w.y + lh * (xa.y - w.y);
        r.z = w.z + lh * (xa.z - w.z);
        r.w = w.w + lh * (xa.w - w.w);
        reinterpret_cast<float4*>(out + (size_t)row * N_FEAT)[t] = r;
    }
}

// ---------------- fallback path (proven 28.7 us, R2) ----------------
__global__ __launch_bounds__(256) void som_dist(
    const float* __restrict__ x, const float* __restrict__ W,
    unsigned long long* __restrict__ keys)
{
    const int row = blockIdx.x;
    const int t   = threadIdx.x;
    const float4 a = reinterpret_cast<const float4*>(x)[t];
    const float4 b = reinterpret_cast<const float4*>(W + (size_t)row * N_FEAT)[t];
    const float dx = a.x - b.x, dy = a.y - b.y, dz = a.z - b.z, dw = a.w - b.w;
    float s = dx * dx + dy * dy + dz * dz + dw * dw;
    #pragma unroll
    for (int o = 32; o > 0; o >>= 1) s += __shfl_down(s, o);
    __shared__ float partial[4];
    if ((t & 63) == 0) partial[t >> 6] = s;
    __syncthreads();
    if (t == 0) {
        const float tot = partial[0] + partial[1] + partial[2] + partial[3];
        keys[row] = ((unsigned long long)__float_as_uint(tot) << 32) | (unsigned)row;
    }
}

__global__ __launch_bounds__(1024) void som_argmin(
    const unsigned long long* __restrict__ keys, unsigned* __restrict__ bmu_out)
{
    const int t = threadIdx.x;
    unsigned long long m = ~0ull;
    for (int i = t; i < N_NEUR; i += 1024) {
        const unsigned long long k = keys[i];
        m = k < m ? k : m;
    }
    #pragma unroll
    for (int o = 32; o > 0; o >>= 1) {
        const unsigned long long k = __shfl_down(m, o);
        m = k < m ? k : m;
    }
    __shared__ unsigned long long wmin[16];
    if ((t & 63) == 0) wmin[t >> 6] = m;
    __syncthreads();
    if (t == 0) {
        #pragma unroll
        for (int w = 1; w < 16; ++w) m = wmin[w] < m ? wmin[w] : m;
        *bmu_out = (unsigned)(m & 0xFFFFFFFFu);
    }
}

__global__ __launch_bounds__(256) void som_update(
    const float* __restrict__ x, const float* __restrict__ W,
    const float* __restrict__ nhb, const unsigned* __restrict__ bmu_ptr,
    float* __restrict__ out)
{
    const int row = blockIdx.x;
    const int t   = threadIdx.x;
    const unsigned bmu = *bmu_ptr;
    const float lh = LR * expf(-0.5f * nhb[(size_t)bmu * N_NEUR + row]);
    const float4 a = reinterpret_cast<const float4*>(x)[t];
    const float4 b = reinterpret_cast<const float4*>(W + (size_t)row * N_FEAT)[t];
    float4 r;
    r.x = b.x + lh * (a.x - b.x);
    r.y = b.y + lh * (a.y - b.y);
    r.z = b.z + lh * (a.z - b.z);
    r.w = b.w + lh * (a.w - b.w);
    reinterpret_cast<float4*>(out + (size_t)row * N_FEAT)[t] = r;
}

extern "C" void kernel_launch(void* const* d_in, const int* in_sizes, int n_in,
                              void* d_out, int out_size, void* d_ws, size_t ws_size,
                              hipStream_t stream)
{
    const float* x   = (const float*)d_in[0];
    const float* W   = (const float*)d_in[1];
    const float* nhb = (const float*)d_in[2];
    float* out       = (float*)d_out;
    unsigned long long* partials = (unsigned long long*)d_ws;

    void* args[] = { (void*)&x, (void*)&W, (void*)&nhb, (void*)&out, (void*)&partials };
    hipError_t err = hipLaunchCooperativeKernel((void*)som_fused, dim3(NBLK),
                                                dim3(NTHR), args, 0, stream);
    if (err != hipSuccess) {
        (void)hipGetLastError();  // clear sticky error; deterministic fallback
        unsigned long long* keys = partials;
        unsigned* bmu            = (unsigned*)(keys + N_NEUR);
        som_dist<<<N_NEUR, 256, 0, stream>>>(x, W, keys);
        som_argmin<<<1, 1024, 0, stream>>>(keys, bmu);
        som_update<<<N_NEUR, 256, 0, stream>>>(x, W, nhb, bmu, out);
    }
}

// Round 5
// 23.541 us; speedup vs baseline: 3.1018x; 3.1018x over previous
//
#include <hip/hip_runtime.h>

#define N_NEUR 9216   // L*L
#define N_FEAT 1024
#define NBLK   1024   // fat blocks: 9 rows each, exact (9216 = 1024*9)
#define ROWS   9
#define LR 0.1f

// ---------------------------------------------------------------------------
// Kernel 1: block b computes dist^2 for rows [b*9, b*9+9), writes ONE packed
// min-key to partials[b]. key = (float_bits(dist2)<<32)|row — dist2 >= 0 so
// IEEE bits are monotone as uint; min key == argmin, ties -> smallest row
// (matches jnp.argmin over the monotone sqrt).
// ---------------------------------------------------------------------------
__global__ __launch_bounds__(256) void som_dist9(
    const float* __restrict__ x, const float* __restrict__ W,
    unsigned long long* __restrict__ partials)
{
    const int b  = blockIdx.x;
    const int t  = threadIdx.x;
    const int wv = t >> 6, ln = t & 63;

    __shared__ float red[4][ROWS];

    const float4 xa = reinterpret_cast<const float4*>(x)[t];

    #pragma unroll
    for (int k = 0; k < ROWS; ++k) {
        const int row = b * ROWS + k;
        const float4 w = reinterpret_cast<const float4*>(W + (size_t)row * N_FEAT)[t];
        const float dx = xa.x - w.x, dy = xa.y - w.y,
                    dz = xa.z - w.z, dw = xa.w - w.w;
        float s = dx * dx + dy * dy + dz * dz + dw * dw;
        #pragma unroll
        for (int o = 32; o > 0; o >>= 1) s += __shfl_down(s, o);
        if (ln == 0) red[wv][k] = s;
    }
    __syncthreads();

    if (t == 0) {
        unsigned long long lmin = ~0ull;
        #pragma unroll
        for (int k = 0; k < ROWS; ++k) {
            const float tot = red[0][k] + red[1][k] + red[2][k] + red[3][k];
            const unsigned long long key =
                ((unsigned long long)__float_as_uint(tot) << 32)
                | (unsigned)(b * ROWS + k);
            lmin = key < lmin ? key : lmin;
        }
        partials[b] = lmin;
    }
}

// ---------------------------------------------------------------------------
// Kernel 2: block b redundantly min-reduces the 1024 partials (8 KB coalesced,
// L2 broadcast) -> bmu, then updates its 9 rows:
//   W_new = W + LR * exp(-nhb[bmu][row]/2) * (x - W)
// W rows were read by the same block index in k1 -> same XCD -> L2-warm.
// ---------------------------------------------------------------------------
__global__ __launch_bounds__(256) void som_update9(
    const float* __restrict__ x, const float* __restrict__ W,
    const float* __restrict__ nhb,
    const unsigned long long* __restrict__ partials,
    float* __restrict__ out)
{
    const int b  = blockIdx.x;
    const int t  = threadIdx.x;
    const int wv = t >> 6, ln = t & 63;

    __shared__ unsigned long long wmin[4];

    unsigned long long m = ~0ull;
    #pragma unroll
    for (int i = 0; i < NBLK / 256; ++i) {
        const unsigned long long k = partials[t + i * 256];
        m = k < m ? k : m;
    }
    #pragma unroll
    for (int o = 32; o > 0; o >>= 1) {
        const unsigned long long k = __shfl_down(m, o);
        m = k < m ? k : m;
    }
    if (ln == 0) wmin[wv] = m;
    __syncthreads();
    m = wmin[0];
    #pragma unroll
    for (int w2 = 1; w2 < 4; ++w2) m = wmin[w2] < m ? wmin[w2] : m;
    const unsigned bmu = (unsigned)(m & 0xFFFFFFFFu);

    const float4 xa = reinterpret_cast<const float4*>(x)[t];

    #pragma unroll
    for (int k = 0; k < ROWS; ++k) {
        const int row = b * ROWS + k;
        const float lh = LR * expf(-0.5f * nhb[(size_t)bmu * N_NEUR + row]);
        const float4 w = reinterpret_cast<const float4*>(W + (size_t)row * N_FEAT)[t];
        float4 r;
        r.x = w.x + lh * (xa.x - w.x);
        r.y = w.y + lh * (xa.y - w.y);
        r.z = w.z + lh * (xa.z - w.z);
        r.w = w.w + lh * (xa.w - w.w);
        reinterpret_cast<float4*>(out + (size_t)row * N_FEAT)[t] = r;
    }
}

extern "C" void kernel_launch(void* const* d_in, const int* in_sizes, int n_in,
                              void* d_out, int out_size, void* d_ws, size_t ws_size,
                              hipStream_t stream)
{
    const float* x   = (const float*)d_in[0];
    const float* W   = (const float*)d_in[1];
    const float* nhb = (const float*)d_in[2];
    float* out       = (float*)d_out;
    unsigned long long* partials = (unsigned long long*)d_ws;

    som_dist9<<<NBLK, 256, 0, stream>>>(x, W, partials);
    som_update9<<<NBLK, 256, 0, stream>>>(x, W, nhb, partials, out);
}

// Round 7
// 22.807 us; speedup vs baseline: 3.2016x; 1.0322x over previous
//
#include <hip/hip_runtime.h>

#define N_NEUR 9216   // L*L
#define N_FEAT 1024
#define NBLK   2304   // 9 blocks/CU: better ramp/drain for streaming
#define ROWS   4      // 9216 = 2304 * 4, exact
#define LR 0.1f

typedef float vfloat4 __attribute__((ext_vector_type(4)));  // clang vector: ok for nontemporal builtins

// ---------------------------------------------------------------------------
// Kernel 1: block b computes dist^2 for rows [b*4, b*4+4), writes ONE packed
// min-key to partials[b]. key = (float_bits(dist2)<<32)|row — dist2 >= 0 so
// IEEE bits are monotone as uint; min key == argmin, ties -> smallest row
// (matches jnp.argmin over the monotone sqrt).
// ---------------------------------------------------------------------------
__global__ __launch_bounds__(256) void som_dist4(
    const float* __restrict__ x, const float* __restrict__ W,
    unsigned long long* __restrict__ partials)
{
    const int b  = blockIdx.x;
    const int t  = threadIdx.x;
    const int wv = t >> 6, ln = t & 63;

    __shared__ float red[4][ROWS];

    const vfloat4 xa = reinterpret_cast<const vfloat4*>(x)[t];

    #pragma unroll
    for (int k = 0; k < ROWS; ++k) {
        const int row = b * ROWS + k;
        const vfloat4 w = reinterpret_cast<const vfloat4*>(W + (size_t)row * N_FEAT)[t];
        const vfloat4 d = xa - w;
        float s = d.x * d.x + d.y * d.y + d.z * d.z + d.w * d.w;
        #pragma unroll
        for (int o = 32; o > 0; o >>= 1) s += __shfl_down(s, o);
        if (ln == 0) red[wv][k] = s;
    }
    __syncthreads();

    if (t == 0) {
        unsigned long long lmin = ~0ull;
        #pragma unroll
        for (int k = 0; k < ROWS; ++k) {
            const float tot = red[0][k] + red[1][k] + red[2][k] + red[3][k];
            const unsigned long long key =
                ((unsigned long long)__float_as_uint(tot) << 32)
                | (unsigned)(b * ROWS + k);
            lmin = key < lmin ? key : lmin;
        }
        partials[b] = lmin;
    }
}

// ---------------------------------------------------------------------------
// Kernel 2: block b prefetches its 4 W rows into registers (independent of
// bmu), then redundantly min-reduces the 2304 partials (18 KB, L2 broadcast)
// -> bmu, then updates:  W_new = W + LR * exp(-nhb[bmu][row]/2) * (x - W).
// out is written with NONTEMPORAL stores: never re-read, keep it from
// evicting W so W stays L2/L3-resident across graph replays.
// ---------------------------------------------------------------------------
__global__ __launch_bounds__(256) void som_update4(
    const float* __restrict__ x, const float* __restrict__ W,
    const float* __restrict__ nhb,
    const unsigned long long* __restrict__ partials,
    float* __restrict__ out)
{
    const int b  = blockIdx.x;
    const int t  = threadIdx.x;
    const int wv = t >> 6, ln = t & 63;

    __shared__ unsigned long long wmin[4];

    const vfloat4 xa = reinterpret_cast<const vfloat4*>(x)[t];

    // prefetch W rows first — loads don't depend on bmu, hide argmin latency
    vfloat4 wrow[ROWS];
    #pragma unroll
    for (int k = 0; k < ROWS; ++k)
        wrow[k] = reinterpret_cast<const vfloat4*>(W + (size_t)(b * ROWS + k) * N_FEAT)[t];

    // redundant argmin over 2304 packed keys (2304 = 9 * 256)
    unsigned long long m = ~0ull;
    #pragma unroll
    for (int i = 0; i < NBLK / 256; ++i) {
        const unsigned long long k = partials[t + i * 256];
        m = k < m ? k : m;
    }
    #pragma unroll
    for (int o = 32; o > 0; o >>= 1) {
        const unsigned long long k = __shfl_down(m, o);
        m = k < m ? k : m;
    }
    if (ln == 0) wmin[wv] = m;
    __syncthreads();
    m = wmin[0];
    #pragma unroll
    for (int w2 = 1; w2 < 4; ++w2) m = wmin[w2] < m ? wmin[w2] : m;
    const unsigned bmu = (unsigned)(m & 0xFFFFFFFFu);

    #pragma unroll
    for (int k = 0; k < ROWS; ++k) {
        const int row = b * ROWS + k;
        const float lh = LR * expf(-0.5f * nhb[(size_t)bmu * N_NEUR + row]);
        const vfloat4 w = wrow[k];
        const vfloat4 r = w + lh * (xa - w);
        __builtin_nontemporal_store(r,
            reinterpret_cast<vfloat4*>(out + (size_t)row * N_FEAT) + t);
    }
}

extern "C" void kernel_launch(void* const* d_in, const int* in_sizes, int n_in,
                              void* d_out, int out_size, void* d_ws, size_t ws_size,
                              hipStream_t stream)
{
    const float* x   = (const float*)d_in[0];
    const float* W   = (const float*)d_in[1];
    const float* nhb = (const float*)d_in[2];
    float* out       = (float*)d_out;
    unsigned long long* partials = (unsigned long long*)d_ws;

    som_dist4<<<NBLK, 256, 0, stream>>>(x, W, partials);
    som_update4<<<NBLK, 256, 0, stream>>>(x, W, nhb, partials, out);
}